// Round 11
// baseline (282.024 us; speedup 1.0000x reference)
//
#include <hip/hip_runtime.h>
#include <math.h>

// ---------------------------------------------------------------------------
// GCN: h1 = relu(Dinv (A+I) Dinv (x@W1) + b1); h2 = relu(Dinv (A+I) Dinv (h1@W2) + b2)
// score = (h2@aw+ab)*sigmoid(h2@mw+mb); out[g] = out_b + sum_v score*(h2@ow)
// R1 CSR gather 2110->567. R2 gemm conflicts ->430. R3 pool fused ->377.
// R5 fill||gemm ->325. R7 ->302. R10: sharded line-padded bin counters +
//     per-bucket counting sort -> dense csr ->277 (best).
// R6/R8 FAILED: multi-phase fused kernels -> 256 VGPR spills.
// R9 FAILED: hot bin counters (100 lines) + serial bucket-agg.
// R11: gathers are latency-bound (VALUBusy ~1%) -> (a) 4-aligned csr regions
//     + int4 index loads (1 load / 4 neighbors, all loads unconditional;
//     zero-filled padding keeps indices safe), (b) unroll-8 named scalars:
//     2 int4 + 8 float4 loads in flight, (c) P-scale pass dropped; gather1
//     uses per-edge dinv (L2-resident) instead.
// ---------------------------------------------------------------------------

#define NB 64              // nodes per bucket (bucket = v >> 6)
#define SEG 16             // counter shards per bucket
#define CAPS 80            // slots per bucket-shard; mean 40, sd 6.3
#define SLOTS (SEG * CAPS) // 1280 slots per bucket
#define BIN_BLOCKS 256

// ---- fused: blocks [0,BIN_BLOCKS) bin edges (+ init out); rest P = x@W1 ----
__global__ __launch_bounds__(256) void gemm_bin_kernel(
    const float* __restrict__ X, const float* __restrict__ W,
    float* __restrict__ P, int N, int K,
    const int* __restrict__ row, const int* __restrict__ col,
    int* __restrict__ bcnt, int* __restrict__ gbuf, int E,
    float* __restrict__ out, const float* __restrict__ out_b, int G) {
    __shared__ float Wl[32 * 64];    // 8 KB
    __shared__ float xs[128 * 33];   // 16.9 KB

    if (blockIdx.x < BIN_BLOCKS) {
        int seg = blockIdx.x & (SEG - 1);
        int t = blockIdx.x * 256 + threadIdx.x;
        if (t < G) out[t] = out_b[0];
        for (int e = t; e < E; e += BIN_BLOCKS * 256) {
            int c = col[e];
            int b = c >> 6;
            // counter padded to its own 64B line: ~40 atomics/line, no hot lines
            int pos = atomicAdd(&bcnt[(b * SEG + seg) * 16], 1);
            if (pos < CAPS) gbuf[b * SLOTS + seg * CAPS + pos] = row[e] | ((c & 63) << 17);
        }
        return;  // uniform per-block branch; never reaches a barrier
    }

    const int tid = threadIdx.x;
    const int cg = tid & 3;
    const int ng = tid >> 2;
    const int node0 = (blockIdx.x - BIN_BLOCKS) * 128;

    float acc[2][16];
#pragma unroll
    for (int r = 0; r < 2; r++)
#pragma unroll
        for (int j = 0; j < 16; j++) acc[r][j] = 0.0f;

    for (int k0 = 0; k0 < K; k0 += 32) {   // runtime loop: keeps VGPR ~64
        const float4* Wg = (const float4*)(W + (size_t)k0 * 64);
#pragma unroll
        for (int f = tid; f < 512; f += 256) ((float4*)Wl)[f] = Wg[f];
        {
            int rrow = tid >> 1;
            int q0 = (tid & 1) * 16;
            int node = node0 + rrow;
            const float* Xr = X + (size_t)node * K + k0 + q0;
            float* xd = &xs[rrow * 33 + q0];
#pragma unroll
            for (int q = 0; q < 4; q++) {
                float4 v = make_float4(0.f, 0.f, 0.f, 0.f);
                if (node < N) v = *(const float4*)(Xr + 4 * q);
                xd[4 * q + 0] = v.x;
                xd[4 * q + 1] = v.y;
                xd[4 * q + 2] = v.z;
                xd[4 * q + 3] = v.w;
            }
        }
        __syncthreads();
#pragma unroll
        for (int kk = 0; kk < 32; kk++) {
            float xv0 = xs[(ng * 2 + 0) * 33 + kk];
            float xv1 = xs[(ng * 2 + 1) * 33 + kk];
            const float* wr = &Wl[kk * 64 + cg * 4];   // 16 distinct banks
            float4 w0 = *(const float4*)(wr + 0);
            float4 w1 = *(const float4*)(wr + 16);
            float4 w2 = *(const float4*)(wr + 32);
            float4 w3 = *(const float4*)(wr + 48);
#pragma unroll
            for (int r = 0; r < 2; r++) {
                float xv = r ? xv1 : xv0;
                acc[r][0]  = fmaf(xv, w0.x, acc[r][0]);
                acc[r][1]  = fmaf(xv, w0.y, acc[r][1]);
                acc[r][2]  = fmaf(xv, w0.z, acc[r][2]);
                acc[r][3]  = fmaf(xv, w0.w, acc[r][3]);
                acc[r][4]  = fmaf(xv, w1.x, acc[r][4]);
                acc[r][5]  = fmaf(xv, w1.y, acc[r][5]);
                acc[r][6]  = fmaf(xv, w1.z, acc[r][6]);
                acc[r][7]  = fmaf(xv, w1.w, acc[r][7]);
                acc[r][8]  = fmaf(xv, w2.x, acc[r][8]);
                acc[r][9]  = fmaf(xv, w2.y, acc[r][9]);
                acc[r][10] = fmaf(xv, w2.z, acc[r][10]);
                acc[r][11] = fmaf(xv, w2.w, acc[r][11]);
                acc[r][12] = fmaf(xv, w3.x, acc[r][12]);
                acc[r][13] = fmaf(xv, w3.y, acc[r][13]);
                acc[r][14] = fmaf(xv, w3.z, acc[r][14]);
                acc[r][15] = fmaf(xv, w3.w, acc[r][15]);
            }
        }
        __syncthreads();
    }

#pragma unroll
    for (int r = 0; r < 2; r++) {
        int node = node0 + ng * 2 + r;
        if (node < N) {
            float* dst = P + (size_t)node * 64 + cg * 4;
#pragma unroll
            for (int m = 0; m < 4; m++) {
                float4 v = make_float4(acc[r][4 * m + 0], acc[r][4 * m + 1],
                                       acc[r][4 * m + 2], acc[r][4 * m + 3]);
                *(float4*)(dst + 16 * m) = v;
            }
        }
    }
}

// ---- per-bucket LDS counting sort: gbuf segments -> dense node-ordered csr
//      with 4-aligned per-node regions (padding pre-zeroed by memset);
//      writes dinv[v] and packed startcnt[v] = (csr_start<<7)|cnt ----
__global__ __launch_bounds__(256) void sort_kernel(
    const int* __restrict__ bcnt, const int* __restrict__ gbuf,
    int* __restrict__ csr, int* __restrict__ startcnt,
    float* __restrict__ dinv, int N) {
    __shared__ int scnt[SEG], segoff[SEG], s_tot;
    __shared__ int ebuf[SLOTS];     // 5 KB
    __shared__ int lcnt[NB], lcur[NB];
    const int tid = threadIdx.x;
    const int b = blockIdx.x;
    const int base = b * SLOTS;

    if (tid < SEG) {
        int c = bcnt[(b * SEG + tid) * 16];
        scnt[tid] = c < CAPS ? c : CAPS;
    }
    if (tid < NB) lcnt[tid] = 0;
    __syncthreads();
    if (tid == 0) {
        int o = 0;
        for (int s = 0; s < SEG; s++) { segoff[s] = o; o += scnt[s]; }
        s_tot = o;
    }
    __syncthreads();
    // compact segments into ebuf + histogram destinations
    for (int idx = tid; idx < SLOTS; idx += 256) {
        int seg = idx / CAPS;
        int j = idx - seg * CAPS;
        if (j < scnt[seg]) {
            int w = gbuf[base + idx];
            ebuf[segoff[seg] + j] = w;
            atomicAdd(&lcnt[(w >> 17) & 63], 1);
        }
    }
    __syncthreads();
    // wave 0: exclusive scan over 4-rounded counts; emit dinv + start|cnt
    if (tid < NB) {
        int cntv = lcnt[tid];
        int rnd = (cntv + 3) & ~3;          // 4-aligned region for int4 loads
        int val = rnd;
#pragma unroll
        for (int off = 1; off < 64; off <<= 1) {
            int n = __shfl_up(val, off, 64);
            if (tid >= off) val += n;
        }
        int st = val - rnd;
        lcur[tid] = st;
        int v = b * NB + tid;
        if (v < N) {
            dinv[v] = rsqrtf(1.0f + (float)cntv);
            int cc = cntv < 127 ? cntv : 127;
            startcnt[v] = ((base + st) << 7) | cc;   // base+st < 2M -> fits
        }
    }
    __syncthreads();
    // scatter to dense node-ordered csr (LDS cursor atomics, dense writes);
    // padding slots stay 0 from the csr memset -> safe int4 over-read
    int tot = s_tot;
    for (int idx = tid; idx < tot; idx += 256) {
        int w = ebuf[idx];
        int vl = (w >> 17) & 63;
        int pp = atomicAdd(&lcur[vl], 1);
        csr[base + pp] = w & 131071;
    }
}

// ---- layer-1 aggregate: B[v] = relu(dv*(dv*P[v] + sum du*P[u]) + bias)
//      int4 index loads + unroll-8 named scalars, all loads unconditional ----
__global__ __launch_bounds__(256) void gather_kernel(
    const float* __restrict__ P, const int* __restrict__ csr,
    const int* __restrict__ startcnt, const float* __restrict__ dinv,
    const float* __restrict__ bias, float* __restrict__ B, int N) {
    int t = blockIdx.x * blockDim.x + threadIdx.x;
    int v = t >> 4;
    if (v >= N) return;
    int p4 = (t & 15) * 4;
    int pack = startcnt[v];
    int st = pack >> 7;           // 4-aligned
    int c = pack & 127;
    float dv = dinv[v];
    float4 a0 = *(const float4*)(P + (size_t)v * 64 + p4);
    float4 acc = make_float4(a0.x * dv, a0.y * dv, a0.z * dv, a0.w * dv);  // self
    for (int i = 0; i < c; i += 8) {
        int4 ua = *(const int4*)(csr + st + i);        // aligned; pad slots = 0
        int4 ub = *(const int4*)(csr + st + i + 4);    // may over-read into 0-pad
        float du0 = dinv[ua.x], du1 = dinv[ua.y], du2 = dinv[ua.z], du3 = dinv[ua.w];
        float du4 = dinv[ub.x], du5 = dinv[ub.y], du6 = dinv[ub.z], du7 = dinv[ub.w];
        float4 m0 = *(const float4*)(P + (size_t)ua.x * 64 + p4);
        float4 m1 = *(const float4*)(P + (size_t)ua.y * 64 + p4);
        float4 m2 = *(const float4*)(P + (size_t)ua.z * 64 + p4);
        float4 m3 = *(const float4*)(P + (size_t)ua.w * 64 + p4);
        float4 m4 = *(const float4*)(P + (size_t)ub.x * 64 + p4);
        float4 m5 = *(const float4*)(P + (size_t)ub.y * 64 + p4);
        float4 m6 = *(const float4*)(P + (size_t)ub.z * 64 + p4);
        float4 m7 = *(const float4*)(P + (size_t)ub.w * 64 + p4);
        acc.x = fmaf(m0.x, du0, acc.x); acc.y = fmaf(m0.y, du0, acc.y);
        acc.z = fmaf(m0.z, du0, acc.z); acc.w = fmaf(m0.w, du0, acc.w);
        if (i + 1 < c) { acc.x = fmaf(m1.x, du1, acc.x); acc.y = fmaf(m1.y, du1, acc.y);
                         acc.z = fmaf(m1.z, du1, acc.z); acc.w = fmaf(m1.w, du1, acc.w); }
        if (i + 2 < c) { acc.x = fmaf(m2.x, du2, acc.x); acc.y = fmaf(m2.y, du2, acc.y);
                         acc.z = fmaf(m2.z, du2, acc.z); acc.w = fmaf(m2.w, du2, acc.w); }
        if (i + 3 < c) { acc.x = fmaf(m3.x, du3, acc.x); acc.y = fmaf(m3.y, du3, acc.y);
                         acc.z = fmaf(m3.z, du3, acc.z); acc.w = fmaf(m3.w, du3, acc.w); }
        if (i + 4 < c) { acc.x = fmaf(m4.x, du4, acc.x); acc.y = fmaf(m4.y, du4, acc.y);
                         acc.z = fmaf(m4.z, du4, acc.z); acc.w = fmaf(m4.w, du4, acc.w); }
        if (i + 5 < c) { acc.x = fmaf(m5.x, du5, acc.x); acc.y = fmaf(m5.y, du5, acc.y);
                         acc.z = fmaf(m5.z, du5, acc.z); acc.w = fmaf(m5.w, du5, acc.w); }
        if (i + 6 < c) { acc.x = fmaf(m6.x, du6, acc.x); acc.y = fmaf(m6.y, du6, acc.y);
                         acc.z = fmaf(m6.z, du6, acc.z); acc.w = fmaf(m6.w, du6, acc.w); }
        if (i + 7 < c) { acc.x = fmaf(m7.x, du7, acc.x); acc.y = fmaf(m7.y, du7, acc.y);
                         acc.z = fmaf(m7.z, du7, acc.z); acc.w = fmaf(m7.w, du7, acc.w); }
    }
    float4 bb = *(const float4*)(bias + p4);
    float4 r;
    r.x = fmaxf(fmaf(acc.x, dv, bb.x), 0.f);
    r.y = fmaxf(fmaf(acc.y, dv, bb.y), 0.f);
    r.z = fmaxf(fmaf(acc.z, dv, bb.z), 0.f);
    r.w = fmaxf(fmaf(acc.w, dv, bb.w), 0.f);
    *(float4*)(B + (size_t)v * 64 + p4) = r;
}

// ---- layer-2 GEMM with dinv epilogue: Q' = dinv[v] * (X @ W) ----
__global__ __launch_bounds__(256) void gemm_scale_kernel(
    const float* __restrict__ X, const float* __restrict__ W,
    const float* __restrict__ dinv, float* __restrict__ Q, int N, int K) {
    __shared__ float Wl[32 * 64];
    __shared__ float xs[128 * 33];
    const int tid = threadIdx.x;
    const int cg = tid & 3;
    const int ng = tid >> 2;
    const int node0 = blockIdx.x * 128;

    float acc[2][16];
#pragma unroll
    for (int r = 0; r < 2; r++)
#pragma unroll
        for (int j = 0; j < 16; j++) acc[r][j] = 0.0f;

    for (int k0 = 0; k0 < K; k0 += 32) {
        const float4* Wg = (const float4*)(W + (size_t)k0 * 64);
#pragma unroll
        for (int f = tid; f < 512; f += 256) ((float4*)Wl)[f] = Wg[f];
        {
            int rrow = tid >> 1;
            int q0 = (tid & 1) * 16;
            int node = node0 + rrow;
            const float* Xr = X + (size_t)node * K + k0 + q0;
            float* xd = &xs[rrow * 33 + q0];
#pragma unroll
            for (int q = 0; q < 4; q++) {
                float4 v = make_float4(0.f, 0.f, 0.f, 0.f);
                if (node < N) v = *(const float4*)(Xr + 4 * q);
                xd[4 * q + 0] = v.x;
                xd[4 * q + 1] = v.y;
                xd[4 * q + 2] = v.z;
                xd[4 * q + 3] = v.w;
            }
        }
        __syncthreads();
#pragma unroll
        for (int kk = 0; kk < 32; kk++) {
            float xv0 = xs[(ng * 2 + 0) * 33 + kk];
            float xv1 = xs[(ng * 2 + 1) * 33 + kk];
            const float* wr = &Wl[kk * 64 + cg * 4];
            float4 w0 = *(const float4*)(wr + 0);
            float4 w1 = *(const float4*)(wr + 16);
            float4 w2 = *(const float4*)(wr + 32);
            float4 w3 = *(const float4*)(wr + 48);
#pragma unroll
            for (int r = 0; r < 2; r++) {
                float xv = r ? xv1 : xv0;
                acc[r][0]  = fmaf(xv, w0.x, acc[r][0]);
                acc[r][1]  = fmaf(xv, w0.y, acc[r][1]);
                acc[r][2]  = fmaf(xv, w0.z, acc[r][2]);
                acc[r][3]  = fmaf(xv, w0.w, acc[r][3]);
                acc[r][4]  = fmaf(xv, w1.x, acc[r][4]);
                acc[r][5]  = fmaf(xv, w1.y, acc[r][5]);
                acc[r][6]  = fmaf(xv, w1.z, acc[r][6]);
                acc[r][7]  = fmaf(xv, w1.w, acc[r][7]);
                acc[r][8]  = fmaf(xv, w2.x, acc[r][8]);
                acc[r][9]  = fmaf(xv, w2.y, acc[r][9]);
                acc[r][10] = fmaf(xv, w2.z, acc[r][10]);
                acc[r][11] = fmaf(xv, w2.w, acc[r][11]);
                acc[r][12] = fmaf(xv, w3.x, acc[r][12]);
                acc[r][13] = fmaf(xv, w3.y, acc[r][13]);
                acc[r][14] = fmaf(xv, w3.z, acc[r][14]);
                acc[r][15] = fmaf(xv, w3.w, acc[r][15]);
            }
        }
        __syncthreads();
    }

#pragma unroll
    for (int r = 0; r < 2; r++) {
        int node = node0 + ng * 2 + r;
        if (node < N) {
            float d = dinv[node];
            float* dst = Q + (size_t)node * 64 + cg * 4;
#pragma unroll
            for (int m = 0; m < 4; m++) {
                float4 v = make_float4(acc[r][4 * m + 0] * d, acc[r][4 * m + 1] * d,
                                       acc[r][4 * m + 2] * d, acc[r][4 * m + 3] * d);
                *(float4*)(dst + 16 * m) = v;
            }
        }
    }
}

// ---- layer-2 aggregate + attention pool + projection (Q pre-scaled) ----
#define GP_NODES 64
__global__ __launch_bounds__(256) void gather_pool_kernel(
    const float* __restrict__ Q, const int* __restrict__ csr,
    const int* __restrict__ startcnt, const float* __restrict__ dinv,
    const float* __restrict__ bias, const int* __restrict__ batch,
    const float* __restrict__ attn_w, const float* __restrict__ attn_b,
    const float* __restrict__ mask_w, const float* __restrict__ mask_b,
    const float* __restrict__ out_w, float* __restrict__ out, int N) {
    __shared__ float pacc[2048];
    __shared__ int s_gmin, s_span;
    const int tid = threadIdx.x;
    const int v0 = blockIdx.x * GP_NODES;
    const int vend = (v0 + GP_NODES < N) ? v0 + GP_NODES : N;
    if (tid == 0) {
        int gmin = batch[v0];
        s_gmin = gmin;
        s_span = batch[vend - 1] - gmin + 1;
    }
    __syncthreads();
    const int gmin = s_gmin, span = s_span;
    for (int i = tid; i < span; i += 256) pacc[i] = 0.f;
    __syncthreads();

    const int p = tid & 15;
    const int p4 = p * 4;
    const float4 wa = ((const float4*)attn_w)[p];
    const float4 wm = ((const float4*)mask_w)[p];
    const float4 wo = ((const float4*)out_w)[p];
    const float4 bb = ((const float4*)bias)[p];
    const float ab = attn_b[0], mb = mask_b[0];

    for (int v = v0 + (tid >> 4); v < vend; v += 16) {
        int pack = startcnt[v];
        int st = pack >> 7;
        int c = pack & 127;
        float dv = dinv[v];
        float4 acc = *(const float4*)(Q + (size_t)v * 64 + p4);   // self (Q' = dv*Q)
        for (int i = 0; i < c; i += 8) {
            int4 ua = *(const int4*)(csr + st + i);
            int4 ub = *(const int4*)(csr + st + i + 4);
            float4 m0 = *(const float4*)(Q + (size_t)ua.x * 64 + p4);
            float4 m1 = *(const float4*)(Q + (size_t)ua.y * 64 + p4);
            float4 m2 = *(const float4*)(Q + (size_t)ua.z * 64 + p4);
            float4 m3 = *(const float4*)(Q + (size_t)ua.w * 64 + p4);
            float4 m4 = *(const float4*)(Q + (size_t)ub.x * 64 + p4);
            float4 m5 = *(const float4*)(Q + (size_t)ub.y * 64 + p4);
            float4 m6 = *(const float4*)(Q + (size_t)ub.z * 64 + p4);
            float4 m7 = *(const float4*)(Q + (size_t)ub.w * 64 + p4);
            acc.x += m0.x; acc.y += m0.y; acc.z += m0.z; acc.w += m0.w;
            if (i + 1 < c) { acc.x += m1.x; acc.y += m1.y; acc.z += m1.z; acc.w += m1.w; }
            if (i + 2 < c) { acc.x += m2.x; acc.y += m2.y; acc.z += m2.z; acc.w += m2.w; }
            if (i + 3 < c) { acc.x += m3.x; acc.y += m3.y; acc.z += m3.z; acc.w += m3.w; }
            if (i + 4 < c) { acc.x += m4.x; acc.y += m4.y; acc.z += m4.z; acc.w += m4.w; }
            if (i + 5 < c) { acc.x += m5.x; acc.y += m5.y; acc.z += m5.z; acc.w += m5.w; }
            if (i + 6 < c) { acc.x += m6.x; acc.y += m6.y; acc.z += m6.z; acc.w += m6.w; }
            if (i + 7 < c) { acc.x += m7.x; acc.y += m7.y; acc.z += m7.z; acc.w += m7.w; }
        }
        float hx = fmaxf(fmaf(acc.x, dv, bb.x), 0.f);
        float hy = fmaxf(fmaf(acc.y, dv, bb.y), 0.f);
        float hz = fmaxf(fmaf(acc.z, dv, bb.z), 0.f);
        float hw = fmaxf(fmaf(acc.w, dv, bb.w), 0.f);
        float pa = hx * wa.x + hy * wa.y + hz * wa.z + hw * wa.w;
        float pm = hx * wm.x + hy * wm.y + hz * wm.z + hw * wm.w;
        float po = hx * wo.x + hy * wo.y + hz * wo.z + hw * wo.w;
#pragma unroll
        for (int off = 1; off < 16; off <<= 1) {   // 16-lane aligned groups
            pa += __shfl_xor(pa, off, 64);
            pm += __shfl_xor(pm, off, 64);
            po += __shfl_xor(po, off, 64);
        }
        if (p == 0) {
            float cc = (pa + ab) * (1.0f / (1.0f + expf(-(pm + mb)))) * po;
            atomicAdd(&pacc[batch[v] - gmin], cc);
        }
    }
    __syncthreads();
    for (int i = tid; i < span; i += 256) {
        float val = pacc[i];
        if (val != 0.f) atomicAdd(&out[gmin + i], val);
    }
}

extern "C" void kernel_launch(void* const* d_in, const int* in_sizes, int n_in,
                              void* d_out, int out_size, void* d_ws, size_t ws_size,
                              hipStream_t stream) {
    const float* x      = (const float*)d_in[0];
    const int*   edge   = (const int*)d_in[1];
    const int*   batch  = (const int*)d_in[2];
    const float* W1     = (const float*)d_in[3];
    const float* b1     = (const float*)d_in[4];
    const float* W2     = (const float*)d_in[5];
    const float* b2     = (const float*)d_in[6];
    const float* attn_w = (const float*)d_in[7];
    const float* attn_b = (const float*)d_in[8];
    const float* mask_w = (const float*)d_in[9];
    const float* mask_b = (const float*)d_in[10];
    const float* out_w  = (const float*)d_in[11];
    const float* out_b  = (const float*)d_in[12];
    float* out = (float*)d_out;

    const int N  = in_sizes[2];
    const int E  = in_sizes[1] / 2;
    const int K1 = in_sizes[0] / N;   // 128
    const int H  = in_sizes[4];       // 64
    const int G  = out_size;          // 2048
    const int* row = edge;            // edge_index[0] = sources
    const int* col = edge + E;        // edge_index[1] = targets

    const int NBUCK = (N + NB - 1) / NB;   // 1563

    // workspace: bcnt 1.6MB + gbuf 8MB + csr 8MB + startcnt/dinv 0.8MB
    //            + P/B/Q 3x25.6MB ~= 95.2MB
    char* ws = (char*)d_ws;
    auto align256 = [](size_t s) { return (s + 255) / 256 * 256; };
    int*   bcnt     = (int*)ws;   ws += align256((size_t)NBUCK * SEG * 16 * 4);
    int*   gbuf     = (int*)ws;   ws += align256((size_t)NBUCK * SLOTS * 4);
    int*   csr      = (int*)ws;   ws += align256((size_t)NBUCK * SLOTS * 4);
    int*   startcnt = (int*)ws;   ws += align256((size_t)N * 4);
    float* dinv     = (float*)ws; ws += align256((size_t)N * 4);
    float* P        = (float*)ws; ws += align256((size_t)N * H * 4);
    float* B        = (float*)ws; ws += align256((size_t)N * H * 4);
    float* Q        = (float*)ws;

    const int gblocks = (N + 127) / 128;
    const int n16b = (N * 16 + 255) / 256;

    hipMemsetAsync(bcnt, 0, (size_t)NBUCK * SEG * 16 * 4, stream);
    hipMemsetAsync(csr, 0, (size_t)NBUCK * SLOTS * 4, stream);  // safe 0-pad for int4 reads

    // fused: sharded edge binning (+out init) || P = x@W1
    gemm_bin_kernel<<<BIN_BLOCKS + gblocks, 256, 0, stream>>>(
        x, W1, P, N, K1, row, col, bcnt, gbuf, E, out, out_b, G);

    // per-bucket counting sort -> dense 4-aligned csr + startcnt + dinv
    sort_kernel<<<NBUCK, 256, 0, stream>>>(bcnt, gbuf, csr, startcnt, dinv, N);

    // layer-1 aggregate: B = relu(dv*(dv*P[v] + sum du*P[u]) + b1)
    gather_kernel<<<n16b, 256, 0, stream>>>(P, csr, startcnt, dinv, b1, B, N);

    // layer-2 GEMM: Q' = dinv * (B @ W2)
    gemm_scale_kernel<<<gblocks, 256, 0, stream>>>(B, W2, dinv, Q, N, H);

    // layer-2 aggregate + attention pool + projection
    gather_pool_kernel<<<NBUCK, 256, 0, stream>>>(
        Q, csr, startcnt, dinv, b2, batch, attn_w, attn_b, mask_w, mask_b, out_w, out, N);
}

// Round 12
// 275.888 us; speedup vs baseline: 1.0222x; 1.0222x over previous
//
#include <hip/hip_runtime.h>
#include <math.h>

// ---------------------------------------------------------------------------
// GCN: h1 = relu(Dinv (A+I) Dinv (x@W1) + b1); h2 = relu(Dinv (A+I) Dinv (h1@W2) + b2)
// score = (h2@aw+ab)*sigmoid(h2@mw+mb); out[g] = out_b + sum_v score*(h2@ow)
// R1 CSR gather 2110->567. R2 gemm conflicts ->430. R3 pool fused ->377.
// R5 fill||gemm ->325. R7 ->302. R10 sharded-counter bins + counting sort ->277.
// R6/R8 FAILED: #pragma-unrolled multi-phase kernels -> 256 VGPR spills.
// R9 FAILED: hot bin counters + serial bucket-agg.
// R11 NEUTRAL (282): int4+unroll-8 gather didn't move the ~212us residual ->
//     gathers are IF$-traffic-bound (256MB random rows/layer), not MLP-bound.
// R12: cut a full pass instead: gemm_scale fused into gather1 (gather_gemm):
//     h1 tile -> LDS (proven 4-nodes-per-group shape, plain loops), then
//     64x64x64 GEMM from LDS with RUNTIME kk-loop (R6/R8 lesson: never
//     #pragma-unroll across phases). Kills the 51MB B round-trip + 1 dispatch.
// ---------------------------------------------------------------------------

#define NB 64              // nodes per bucket (bucket = v >> 6)
#define SEG 16             // counter shards per bucket
#define CAPS 80            // slots per bucket-shard; mean 40, sd 6.3
#define SLOTS (SEG * CAPS) // 1280 slots per bucket
#define BIN_BLOCKS 256

// ---- fused: blocks [0,BIN_BLOCKS) bin edges (+ init out); rest P = x@W1 ----
__global__ __launch_bounds__(256) void gemm_bin_kernel(
    const float* __restrict__ X, const float* __restrict__ W,
    float* __restrict__ P, int N, int K,
    const int* __restrict__ row, const int* __restrict__ col,
    int* __restrict__ bcnt, int* __restrict__ gbuf, int E,
    float* __restrict__ out, const float* __restrict__ out_b, int G) {
    __shared__ float Wl[32 * 64];    // 8 KB
    __shared__ float xs[128 * 33];   // 16.9 KB

    if (blockIdx.x < BIN_BLOCKS) {
        int seg = blockIdx.x & (SEG - 1);
        int t = blockIdx.x * 256 + threadIdx.x;
        if (t < G) out[t] = out_b[0];
        for (int e = t; e < E; e += BIN_BLOCKS * 256) {
            int c = col[e];
            int b = c >> 6;
            // counter padded to its own 64B line: ~40 atomics/line, no hot lines
            int pos = atomicAdd(&bcnt[(b * SEG + seg) * 16], 1);
            if (pos < CAPS) gbuf[b * SLOTS + seg * CAPS + pos] = row[e] | ((c & 63) << 17);
        }
        return;  // uniform per-block branch; never reaches a barrier
    }

    const int tid = threadIdx.x;
    const int cg = tid & 3;
    const int ng = tid >> 2;
    const int node0 = (blockIdx.x - BIN_BLOCKS) * 128;

    float acc[2][16];
#pragma unroll
    for (int r = 0; r < 2; r++)
#pragma unroll
        for (int j = 0; j < 16; j++) acc[r][j] = 0.0f;

    for (int k0 = 0; k0 < K; k0 += 32) {   // runtime loop: keeps VGPR ~64
        const float4* Wg = (const float4*)(W + (size_t)k0 * 64);
#pragma unroll
        for (int f = tid; f < 512; f += 256) ((float4*)Wl)[f] = Wg[f];
        {
            int rrow = tid >> 1;
            int q0 = (tid & 1) * 16;
            int node = node0 + rrow;
            const float* Xr = X + (size_t)node * K + k0 + q0;
            float* xd = &xs[rrow * 33 + q0];
#pragma unroll
            for (int q = 0; q < 4; q++) {
                float4 v = make_float4(0.f, 0.f, 0.f, 0.f);
                if (node < N) v = *(const float4*)(Xr + 4 * q);
                xd[4 * q + 0] = v.x;
                xd[4 * q + 1] = v.y;
                xd[4 * q + 2] = v.z;
                xd[4 * q + 3] = v.w;
            }
        }
        __syncthreads();
#pragma unroll
        for (int kk = 0; kk < 32; kk++) {
            float xv0 = xs[(ng * 2 + 0) * 33 + kk];
            float xv1 = xs[(ng * 2 + 1) * 33 + kk];
            const float* wr = &Wl[kk * 64 + cg * 4];   // 16 distinct banks
            float4 w0 = *(const float4*)(wr + 0);
            float4 w1 = *(const float4*)(wr + 16);
            float4 w2 = *(const float4*)(wr + 32);
            float4 w3 = *(const float4*)(wr + 48);
#pragma unroll
            for (int r = 0; r < 2; r++) {
                float xv = r ? xv1 : xv0;
                acc[r][0]  = fmaf(xv, w0.x, acc[r][0]);
                acc[r][1]  = fmaf(xv, w0.y, acc[r][1]);
                acc[r][2]  = fmaf(xv, w0.z, acc[r][2]);
                acc[r][3]  = fmaf(xv, w0.w, acc[r][3]);
                acc[r][4]  = fmaf(xv, w1.x, acc[r][4]);
                acc[r][5]  = fmaf(xv, w1.y, acc[r][5]);
                acc[r][6]  = fmaf(xv, w1.z, acc[r][6]);
                acc[r][7]  = fmaf(xv, w1.w, acc[r][7]);
                acc[r][8]  = fmaf(xv, w2.x, acc[r][8]);
                acc[r][9]  = fmaf(xv, w2.y, acc[r][9]);
                acc[r][10] = fmaf(xv, w2.z, acc[r][10]);
                acc[r][11] = fmaf(xv, w2.w, acc[r][11]);
                acc[r][12] = fmaf(xv, w3.x, acc[r][12]);
                acc[r][13] = fmaf(xv, w3.y, acc[r][13]);
                acc[r][14] = fmaf(xv, w3.z, acc[r][14]);
                acc[r][15] = fmaf(xv, w3.w, acc[r][15]);
            }
        }
        __syncthreads();
    }

#pragma unroll
    for (int r = 0; r < 2; r++) {
        int node = node0 + ng * 2 + r;
        if (node < N) {
            float* dst = P + (size_t)node * 64 + cg * 4;
#pragma unroll
            for (int m = 0; m < 4; m++) {
                float4 v = make_float4(acc[r][4 * m + 0], acc[r][4 * m + 1],
                                       acc[r][4 * m + 2], acc[r][4 * m + 3]);
                *(float4*)(dst + 16 * m) = v;
            }
        }
    }
}

// ---- per-bucket LDS counting sort: gbuf segments -> dense node-ordered csr
//      with 4-aligned per-node regions (padding pre-zeroed by memset);
//      writes dinv[v] and packed startcnt[v] = (csr_start<<7)|cnt ----
__global__ __launch_bounds__(256) void sort_kernel(
    const int* __restrict__ bcnt, const int* __restrict__ gbuf,
    int* __restrict__ csr, int* __restrict__ startcnt,
    float* __restrict__ dinv, int N) {
    __shared__ int scnt[SEG], segoff[SEG], s_tot;
    __shared__ int ebuf[SLOTS];     // 5 KB
    __shared__ int lcnt[NB], lcur[NB];
    const int tid = threadIdx.x;
    const int b = blockIdx.x;
    const int base = b * SLOTS;

    if (tid < SEG) {
        int c = bcnt[(b * SEG + tid) * 16];
        scnt[tid] = c < CAPS ? c : CAPS;
    }
    if (tid < NB) lcnt[tid] = 0;
    __syncthreads();
    if (tid == 0) {
        int o = 0;
        for (int s = 0; s < SEG; s++) { segoff[s] = o; o += scnt[s]; }
        s_tot = o;
    }
    __syncthreads();
    // compact segments into ebuf + histogram destinations
    for (int idx = tid; idx < SLOTS; idx += 256) {
        int seg = idx / CAPS;
        int j = idx - seg * CAPS;
        if (j < scnt[seg]) {
            int w = gbuf[base + idx];
            ebuf[segoff[seg] + j] = w;
            atomicAdd(&lcnt[(w >> 17) & 63], 1);
        }
    }
    __syncthreads();
    // wave 0: exclusive scan over 4-rounded counts; emit dinv + start|cnt
    if (tid < NB) {
        int cntv = lcnt[tid];
        int rnd = (cntv + 3) & ~3;          // 4-aligned region for int4 loads
        int val = rnd;
#pragma unroll
        for (int off = 1; off < 64; off <<= 1) {
            int n = __shfl_up(val, off, 64);
            if (tid >= off) val += n;
        }
        int st = val - rnd;
        lcur[tid] = st;
        int v = b * NB + tid;
        if (v < N) {
            dinv[v] = rsqrtf(1.0f + (float)cntv);
            int cc = cntv < 127 ? cntv : 127;
            startcnt[v] = ((base + st) << 7) | cc;   // base+st < 2M -> fits
        }
    }
    __syncthreads();
    // scatter to dense node-ordered csr (LDS cursor atomics, dense writes);
    // padding slots stay 0 from the csr memset -> safe int4 over-read
    int tot = s_tot;
    for (int idx = tid; idx < tot; idx += 256) {
        int w = ebuf[idx];
        int vl = (w >> 17) & 63;
        int pp = atomicAdd(&lcur[vl], 1);
        csr[base + pp] = w & 131071;
    }
}

// ---- fused layer-1 aggregate + layer-2 GEMM ----
// Block = 64 nodes (one bucket). Phase 1: gather h1 into LDS hs[64][65]
// (4 nodes per 16-lane group, plain v-loop — R7/R10-proven shape).
// Phase 2: Q' = dinv * (h1 @ W2) with RUNTIME kk-loop (no cross-phase unroll).
__global__ __launch_bounds__(256) void gather_gemm_kernel(
    const float* __restrict__ P, const int* __restrict__ csr,
    const int* __restrict__ startcnt, const float* __restrict__ dinv,
    const float* __restrict__ b1, const float* __restrict__ W2,
    float* __restrict__ Q, int N) {
    __shared__ float hs[64 * 65];   // 16.6 KB h1 tile
    __shared__ float Wl[64 * 64];   // 16 KB full W2
    const int tid = threadIdx.x;
    const int v0 = blockIdx.x * 64;
    const int vend = (v0 + 64 < N) ? v0 + 64 : N;
    const int p = tid & 15;
    const int p4 = p * 4;

    // stage W2 early; loads retire under the gather phase
    for (int f = tid; f < 1024; f += 256)
        ((float4*)Wl)[f] = ((const float4*)W2)[f];

    const float4 bb = ((const float4*)b1)[p];
    for (int v = v0 + (tid >> 4); v < vend; v += 16) {   // plain loop
        int pack = startcnt[v];
        int st = pack >> 7;           // 4-aligned
        int c = pack & 127;
        float dv = dinv[v];
        float4 a0 = *(const float4*)(P + (size_t)v * 64 + p4);
        float4 acc = make_float4(a0.x * dv, a0.y * dv, a0.z * dv, a0.w * dv);
        for (int i = 0; i < c; i += 8) {
            int4 ua = *(const int4*)(csr + st + i);      // pad slots = 0, safe
            int4 ub = *(const int4*)(csr + st + i + 4);
            float du0 = dinv[ua.x], du1 = dinv[ua.y], du2 = dinv[ua.z], du3 = dinv[ua.w];
            float du4 = dinv[ub.x], du5 = dinv[ub.y], du6 = dinv[ub.z], du7 = dinv[ub.w];
            float4 m0 = *(const float4*)(P + (size_t)ua.x * 64 + p4);
            float4 m1 = *(const float4*)(P + (size_t)ua.y * 64 + p4);
            float4 m2 = *(const float4*)(P + (size_t)ua.z * 64 + p4);
            float4 m3 = *(const float4*)(P + (size_t)ua.w * 64 + p4);
            float4 m4 = *(const float4*)(P + (size_t)ub.x * 64 + p4);
            float4 m5 = *(const float4*)(P + (size_t)ub.y * 64 + p4);
            float4 m6 = *(const float4*)(P + (size_t)ub.z * 64 + p4);
            float4 m7 = *(const float4*)(P + (size_t)ub.w * 64 + p4);
            acc.x = fmaf(m0.x, du0, acc.x); acc.y = fmaf(m0.y, du0, acc.y);
            acc.z = fmaf(m0.z, du0, acc.z); acc.w = fmaf(m0.w, du0, acc.w);
            if (i + 1 < c) { acc.x = fmaf(m1.x, du1, acc.x); acc.y = fmaf(m1.y, du1, acc.y);
                             acc.z = fmaf(m1.z, du1, acc.z); acc.w = fmaf(m1.w, du1, acc.w); }
            if (i + 2 < c) { acc.x = fmaf(m2.x, du2, acc.x); acc.y = fmaf(m2.y, du2, acc.y);
                             acc.z = fmaf(m2.z, du2, acc.z); acc.w = fmaf(m2.w, du2, acc.w); }
            if (i + 3 < c) { acc.x = fmaf(m3.x, du3, acc.x); acc.y = fmaf(m3.y, du3, acc.y);
                             acc.z = fmaf(m3.z, du3, acc.z); acc.w = fmaf(m3.w, du3, acc.w); }
            if (i + 4 < c) { acc.x = fmaf(m4.x, du4, acc.x); acc.y = fmaf(m4.y, du4, acc.y);
                             acc.z = fmaf(m4.z, du4, acc.z); acc.w = fmaf(m4.w, du4, acc.w); }
            if (i + 5 < c) { acc.x = fmaf(m5.x, du5, acc.x); acc.y = fmaf(m5.y, du5, acc.y);
                             acc.z = fmaf(m5.z, du5, acc.z); acc.w = fmaf(m5.w, du5, acc.w); }
            if (i + 6 < c) { acc.x = fmaf(m6.x, du6, acc.x); acc.y = fmaf(m6.y, du6, acc.y);
                             acc.z = fmaf(m6.z, du6, acc.z); acc.w = fmaf(m6.w, du6, acc.w); }
            if (i + 7 < c) { acc.x = fmaf(m7.x, du7, acc.x); acc.y = fmaf(m7.y, du7, acc.y);
                             acc.z = fmaf(m7.z, du7, acc.z); acc.w = fmaf(m7.w, du7, acc.w); }
        }
        float* hd = &hs[(v - v0) * 65 + p4];
        hd[0] = fmaxf(fmaf(acc.x, dv, bb.x), 0.f);
        hd[1] = fmaxf(fmaf(acc.y, dv, bb.y), 0.f);
        hd[2] = fmaxf(fmaf(acc.z, dv, bb.z), 0.f);
        hd[3] = fmaxf(fmaf(acc.w, dv, bb.w), 0.f);
    }
    __syncthreads();

    // Phase 2: Q'[v0+n0] = dinv * (hs[n0] @ W2); 65-pad -> banks n0+kk: conflict-free
    const int cg = tid & 3;
    const int n0 = tid >> 2;
    float acc[16];
#pragma unroll
    for (int j = 0; j < 16; j++) acc[j] = 0.0f;
    for (int kk = 0; kk < 64; kk++) {     // RUNTIME loop (R6/R8 lesson)
        float xv = hs[n0 * 65 + kk];
        const float* wr = &Wl[kk * 64 + cg * 4];
        float4 w0 = *(const float4*)(wr + 0);
        float4 w1 = *(const float4*)(wr + 16);
        float4 w2 = *(const float4*)(wr + 32);
        float4 w3 = *(const float4*)(wr + 48);
        acc[0]  = fmaf(xv, w0.x, acc[0]);
        acc[1]  = fmaf(xv, w0.y, acc[1]);
        acc[2]  = fmaf(xv, w0.z, acc[2]);
        acc[3]  = fmaf(xv, w0.w, acc[3]);
        acc[4]  = fmaf(xv, w1.x, acc[4]);
        acc[5]  = fmaf(xv, w1.y, acc[5]);
        acc[6]  = fmaf(xv, w1.z, acc[6]);
        acc[7]  = fmaf(xv, w1.w, acc[7]);
        acc[8]  = fmaf(xv, w2.x, acc[8]);
        acc[9]  = fmaf(xv, w2.y, acc[9]);
        acc[10] = fmaf(xv, w2.z, acc[10]);
        acc[11] = fmaf(xv, w2.w, acc[11]);
        acc[12] = fmaf(xv, w3.x, acc[12]);
        acc[13] = fmaf(xv, w3.y, acc[13]);
        acc[14] = fmaf(xv, w3.z, acc[14]);
        acc[15] = fmaf(xv, w3.w, acc[15]);
    }
    int node = v0 + n0;
    if (node < N) {
        float d = dinv[node];
        float* dst = Q + (size_t)node * 64 + cg * 4;
        for (int m = 0; m < 4; m++) {
            float4 v = make_float4(acc[4 * m + 0] * d, acc[4 * m + 1] * d,
                                   acc[4 * m + 2] * d, acc[4 * m + 3] * d);
            *(float4*)(dst + 16 * m) = v;
        }
    }
}

// ---- layer-2 aggregate + attention pool + projection (Q pre-scaled) ----
#define GP_NODES 64
__global__ __launch_bounds__(256) void gather_pool_kernel(
    const float* __restrict__ Q, const int* __restrict__ csr,
    const int* __restrict__ startcnt, const float* __restrict__ dinv,
    const float* __restrict__ bias, const int* __restrict__ batch,
    const float* __restrict__ attn_w, const float* __restrict__ attn_b,
    const float* __restrict__ mask_w, const float* __restrict__ mask_b,
    const float* __restrict__ out_w, float* __restrict__ out, int N) {
    __shared__ float pacc[2048];
    __shared__ int s_gmin, s_span;
    const int tid = threadIdx.x;
    const int v0 = blockIdx.x * GP_NODES;
    const int vend = (v0 + GP_NODES < N) ? v0 + GP_NODES : N;
    if (tid == 0) {
        int gmin = batch[v0];
        s_gmin = gmin;
        s_span = batch[vend - 1] - gmin + 1;
    }
    __syncthreads();
    const int gmin = s_gmin, span = s_span;
    for (int i = tid; i < span; i += 256) pacc[i] = 0.f;
    __syncthreads();

    const int p = tid & 15;
    const int p4 = p * 4;
    const float4 wa = ((const float4*)attn_w)[p];
    const float4 wm = ((const float4*)mask_w)[p];
    const float4 wo = ((const float4*)out_w)[p];
    const float4 bb = ((const float4*)bias)[p];
    const float ab = attn_b[0], mb = mask_b[0];

    for (int v = v0 + (tid >> 4); v < vend; v += 16) {
        int pack = startcnt[v];
        int st = pack >> 7;
        int c = pack & 127;
        float dv = dinv[v];
        float4 acc = *(const float4*)(Q + (size_t)v * 64 + p4);   // self (Q' = dv*Q)
        for (int i = 0; i < c; i += 8) {
            int4 ua = *(const int4*)(csr + st + i);
            int4 ub = *(const int4*)(csr + st + i + 4);
            float4 m0 = *(const float4*)(Q + (size_t)ua.x * 64 + p4);
            float4 m1 = *(const float4*)(Q + (size_t)ua.y * 64 + p4);
            float4 m2 = *(const float4*)(Q + (size_t)ua.z * 64 + p4);
            float4 m3 = *(const float4*)(Q + (size_t)ua.w * 64 + p4);
            float4 m4 = *(const float4*)(Q + (size_t)ub.x * 64 + p4);
            float4 m5 = *(const float4*)(Q + (size_t)ub.y * 64 + p4);
            float4 m6 = *(const float4*)(Q + (size_t)ub.z * 64 + p4);
            float4 m7 = *(const float4*)(Q + (size_t)ub.w * 64 + p4);
            acc.x += m0.x; acc.y += m0.y; acc.z += m0.z; acc.w += m0.w;
            if (i + 1 < c) { acc.x += m1.x; acc.y += m1.y; acc.z += m1.z; acc.w += m1.w; }
            if (i + 2 < c) { acc.x += m2.x; acc.y += m2.y; acc.z += m2.z; acc.w += m2.w; }
            if (i + 3 < c) { acc.x += m3.x; acc.y += m3.y; acc.z += m3.z; acc.w += m3.w; }
            if (i + 4 < c) { acc.x += m4.x; acc.y += m4.y; acc.z += m4.z; acc.w += m4.w; }
            if (i + 5 < c) { acc.x += m5.x; acc.y += m5.y; acc.z += m5.z; acc.w += m5.w; }
            if (i + 6 < c) { acc.x += m6.x; acc.y += m6.y; acc.z += m6.z; acc.w += m6.w; }
            if (i + 7 < c) { acc.x += m7.x; acc.y += m7.y; acc.z += m7.z; acc.w += m7.w; }
        }
        float hx = fmaxf(fmaf(acc.x, dv, bb.x), 0.f);
        float hy = fmaxf(fmaf(acc.y, dv, bb.y), 0.f);
        float hz = fmaxf(fmaf(acc.z, dv, bb.z), 0.f);
        float hw = fmaxf(fmaf(acc.w, dv, bb.w), 0.f);
        float pa = hx * wa.x + hy * wa.y + hz * wa.z + hw * wa.w;
        float pm = hx * wm.x + hy * wm.y + hz * wm.z + hw * wm.w;
        float po = hx * wo.x + hy * wo.y + hz * wo.z + hw * wo.w;
#pragma unroll
        for (int off = 1; off < 16; off <<= 1) {   // 16-lane aligned groups
            pa += __shfl_xor(pa, off, 64);
            pm += __shfl_xor(pm, off, 64);
            po += __shfl_xor(po, off, 64);
        }
        if (p == 0) {
            float cc = (pa + ab) * (1.0f / (1.0f + expf(-(pm + mb)))) * po;
            atomicAdd(&pacc[batch[v] - gmin], cc);
        }
    }
    __syncthreads();
    for (int i = tid; i < span; i += 256) {
        float val = pacc[i];
        if (val != 0.f) atomicAdd(&out[gmin + i], val);
    }
}

extern "C" void kernel_launch(void* const* d_in, const int* in_sizes, int n_in,
                              void* d_out, int out_size, void* d_ws, size_t ws_size,
                              hipStream_t stream) {
    const float* x      = (const float*)d_in[0];
    const int*   edge   = (const int*)d_in[1];
    const int*   batch  = (const int*)d_in[2];
    const float* W1     = (const float*)d_in[3];
    const float* b1     = (const float*)d_in[4];
    const float* W2     = (const float*)d_in[5];
    const float* b2     = (const float*)d_in[6];
    const float* attn_w = (const float*)d_in[7];
    const float* attn_b = (const float*)d_in[8];
    const float* mask_w = (const float*)d_in[9];
    const float* mask_b = (const float*)d_in[10];
    const float* out_w  = (const float*)d_in[11];
    const float* out_b  = (const float*)d_in[12];
    float* out = (float*)d_out;

    const int N  = in_sizes[2];
    const int E  = in_sizes[1] / 2;
    const int K1 = in_sizes[0] / N;   // 128
    const int H  = in_sizes[4];       // 64
    const int G  = out_size;          // 2048
    const int* row = edge;            // edge_index[0] = sources
    const int* col = edge + E;        // edge_index[1] = targets

    const int NBUCK = (N + NB - 1) / NB;   // 1563

    // workspace: bcnt 1.6MB + gbuf 8MB + csr 8MB + startcnt/dinv 0.8MB
    //            + P/Q 2x25.6MB ~= 69.6MB
    char* ws = (char*)d_ws;
    auto align256 = [](size_t s) { return (s + 255) / 256 * 256; };
    int*   bcnt     = (int*)ws;   ws += align256((size_t)NBUCK * SEG * 16 * 4);
    int*   gbuf     = (int*)ws;   ws += align256((size_t)NBUCK * SLOTS * 4);
    int*   csr      = (int*)ws;   ws += align256((size_t)NBUCK * SLOTS * 4);
    int*   startcnt = (int*)ws;   ws += align256((size_t)N * 4);
    float* dinv     = (float*)ws; ws += align256((size_t)N * 4);
    float* P        = (float*)ws; ws += align256((size_t)N * H * 4);
    float* Q        = (float*)ws;

    const int gblocks = (N + 127) / 128;

    hipMemsetAsync(bcnt, 0, (size_t)NBUCK * SEG * 16 * 4, stream);
    hipMemsetAsync(csr, 0, (size_t)NBUCK * SLOTS * 4, stream);  // 0-pad for int4 reads

    // fused: sharded edge binning (+out init) || P = x@W1
    gemm_bin_kernel<<<BIN_BLOCKS + gblocks, 256, 0, stream>>>(
        x, W1, P, N, K1, row, col, bcnt, gbuf, E, out, out_b, G);

    // per-bucket counting sort -> dense 4-aligned csr + startcnt + dinv
    sort_kernel<<<NBUCK, 256, 0, stream>>>(bcnt, gbuf, csr, startcnt, dinv, N);

    // fused layer-1 aggregate (h1 -> LDS) + layer-2 GEMM: Q' = dinv*(h1@W2)
    gather_gemm_kernel<<<NBUCK, 256, 0, stream>>>(
        P, csr, startcnt, dinv, b1, W2, Q, N);

    // layer-2 aggregate + attention pool + projection
    gather_pool_kernel<<<NBUCK, 256, 0, stream>>>(
        Q, csr, startcnt, dinv, b2, batch, attn_w, attn_b, mask_w, mask_b, out_w, out, N);
}